// Round 2
// baseline (59914.386 us; speedup 1.0000x reference)
//
#include <hip/hip_runtime.h>

typedef unsigned short u16;
typedef unsigned int u32;

#define BATCH 256
#define TT 512
#define HID 256
#define GATES 1024   // 4*HID
#define NEMB 512
#define VOC 27

__device__ __forceinline__ float bf1(u16 x){ union{u32 u; float f;} v; v.u = ((u32)x) << 16; return v.f; }
__device__ __forceinline__ u16 f2bf(float f){
  union{float f; u32 u;} v; v.f = f;
  u32 u = v.u;
  return (u16)((u + 0x7fffu + ((u >> 16) & 1u)) >> 16);
}
__device__ __forceinline__ float sigm(float x){ return 1.f / (1.f + __expf(-x)); }

// Sniff storage dtype of b_ih0 (1024 elems, |v| <= 1/16).
// Scan even u16 halfwords of the first 2048 bytes (in-bounds for both dtypes).
// bf16 storage: every scanned halfword is a real value, exponent field <= 122.
// f32 storage: scanned halfwords are low mantissa bits ~ random; some will have
// exponent field >= 127. flag: 1 = bf16 storage, 0 = f32 storage.
__global__ void k_detect(const u16* __restrict__ b, int* __restrict__ flag) {
  int bad = 0;
  for (int k = threadIdx.x; k < 512; k += 64)
    if (((b[2 * k] >> 7) & 0xFF) >= 127) bad = 1;
  unsigned long long m = __ballot(bad);   // single wave
  if (threadIdx.x == 0) flag[0] = (m != 0ULL) ? 0 : 1;
}

__global__ void k_convert(const void* __restrict__ src, float* __restrict__ dst,
                          int n, const int* __restrict__ flag) {
  int i = blockIdx.x * 256 + threadIdx.x;
  if (i >= n) return;
  dst[i] = flag[0] ? bf1(((const u16*)src)[i]) : ((const float*)src)[i];
}

// W0emb[v][g] = sum_i emb[v][i]*w_ih0[g][i] + b_ih0[g] + b_hh0[g]; emb row 26 := 0
__global__ void k_prep(const void* __restrict__ emb, const void* __restrict__ wih,
                       const void* __restrict__ bih, const void* __restrict__ bhh,
                       const int* __restrict__ flag, float* __restrict__ W0) {
  int idx = blockIdx.x * 256 + threadIdx.x;
  if (idx >= VOC * GATES) return;
  int v = idx >> 10, g = idx & (GATES - 1);
  int isbf = flag[0];
  float acc = isbf ? (bf1(((const u16*)bih)[g]) + bf1(((const u16*)bhh)[g]))
                   : (((const float*)bih)[g] + ((const float*)bhh)[g]);
  if (v != 26) {
    float s = 0.f;
    if (isbf) {
      const u16* e = (const u16*)emb + v * NEMB;
      const u16* w = (const u16*)wih + g * NEMB;
      for (int i = 0; i < NEMB; i++) s = fmaf(bf1(e[i]), bf1(w[i]), s);
    } else {
      const float* e = (const float*)emb + v * NEMB;
      const float* w = (const float*)wih + g * NEMB;
      for (int i = 0; i < NEMB; i++) s = fmaf(e[i], w[i], s);
    }
    acc += s;
  }
  W0[idx] = acc;
}

// One timestep of layer 0. grid = 256 blocks (64 batch-groups x 4 j-chunks), 512 thr.
// tg=0: gates i,f ; tg=1: gates g,o ; tg=0 does the c/h update.
__global__ __launch_bounds__(512) void k_step0(
    const int* __restrict__ ids, const float* __restrict__ W0,
    const float* __restrict__ whh,
    const float* __restrict__ h_cur, float* __restrict__ h_nxt,
    float* __restrict__ c, int t) {
  int bg = blockIdx.x >> 2, jc = blockIdx.x & 3;
  int tb = (threadIdx.x >> 6) & 3, tj = threadIdx.x & 63, tg = threadIdx.x >> 8;
  int b = bg * 4 + tb, j = jc * 64 + tj;

  __shared__ float h_s[4 * HID];
  __shared__ float acc_s[4][64][2];
  for (int i = threadIdx.x; i < 4 * HID; i += 512) h_s[i] = h_cur[bg * (4 * HID) + i];
  __syncthreads();

  int row0 = j + tg * 512;          // i (tg=0) or g (tg=1)
  int row1 = j + 256 + tg * 512;    // f (tg=0) or o (tg=1)
  const float* xg = W0 + ids[b * TT + t] * GATES;
  float a0 = xg[row0], a1 = xg[row1];

  const float* w0 = whh + row0 * HID;
  const float* w1 = whh + row1 * HID;
  const float* hh = h_s + tb * HID;
  #pragma unroll 8
  for (int k = 0; k < HID; k += 4) {
    float4 q0 = *(const float4*)(w0 + k);
    float4 q1 = *(const float4*)(w1 + k);
    float4 hv = *(const float4*)(hh + k);
    a0 = fmaf(q0.x, hv.x, a0); a0 = fmaf(q0.y, hv.y, a0);
    a0 = fmaf(q0.z, hv.z, a0); a0 = fmaf(q0.w, hv.w, a0);
    a1 = fmaf(q1.x, hv.x, a1); a1 = fmaf(q1.y, hv.y, a1);
    a1 = fmaf(q1.z, hv.z, a1); a1 = fmaf(q1.w, hv.w, a1);
  }

  if (tg) { acc_s[tb][tj][0] = a0; acc_s[tb][tj][1] = a1; }
  __syncthreads();
  if (!tg) {
    float gi = sigm(a0), gf = sigm(a1);
    float gg = tanhf(acc_s[tb][tj][0]);
    float go = sigm(acc_s[tb][tj][1]);
    int off = b * HID + j;
    float cv = fmaf(gf, c[off], gi * gg);
    c[off] = cv;
    h_nxt[off] = go * tanhf(cv);
  }
}

// One timestep of layer 1 (x@wih^T fused, K=512 total).
__global__ __launch_bounds__(512) void k_step1(
    const float* __restrict__ x_t,
    const float* __restrict__ wih, const float* __restrict__ whh,
    const float* __restrict__ bih, const float* __restrict__ bhh,
    const float* __restrict__ h_cur, float* __restrict__ h_nxt,
    float* __restrict__ c) {
  int bg = blockIdx.x >> 2, jc = blockIdx.x & 3;
  int tb = (threadIdx.x >> 6) & 3, tj = threadIdx.x & 63, tg = threadIdx.x >> 8;
  int b = bg * 4 + tb, j = jc * 64 + tj;

  __shared__ float x_s[4 * HID];
  __shared__ float h_s[4 * HID];
  __shared__ float acc_s[4][64][2];
  for (int i = threadIdx.x; i < 4 * HID; i += 512) {
    x_s[i] = x_t[bg * (4 * HID) + i];
    h_s[i] = h_cur[bg * (4 * HID) + i];
  }
  __syncthreads();

  int row0 = j + tg * 512;
  int row1 = j + 256 + tg * 512;
  float a0 = bih[row0] + bhh[row0];
  float a1 = bih[row1] + bhh[row1];

  const float* wi0 = wih + row0 * HID;
  const float* wi1 = wih + row1 * HID;
  const float* wh0 = whh + row0 * HID;
  const float* wh1 = whh + row1 * HID;
  const float* xx = x_s + tb * HID;
  const float* hh = h_s + tb * HID;
  #pragma unroll 4
  for (int k = 0; k < HID; k += 4) {
    float4 qi0 = *(const float4*)(wi0 + k);
    float4 qi1 = *(const float4*)(wi1 + k);
    float4 qh0 = *(const float4*)(wh0 + k);
    float4 qh1 = *(const float4*)(wh1 + k);
    float4 xv = *(const float4*)(xx + k);
    float4 hv = *(const float4*)(hh + k);
    a0 = fmaf(qi0.x, xv.x, a0); a0 = fmaf(qi0.y, xv.y, a0);
    a0 = fmaf(qi0.z, xv.z, a0); a0 = fmaf(qi0.w, xv.w, a0);
    a1 = fmaf(qi1.x, xv.x, a1); a1 = fmaf(qi1.y, xv.y, a1);
    a1 = fmaf(qi1.z, xv.z, a1); a1 = fmaf(qi1.w, xv.w, a1);
    a0 = fmaf(qh0.x, hv.x, a0); a0 = fmaf(qh0.y, hv.y, a0);
    a0 = fmaf(qh0.z, hv.z, a0); a0 = fmaf(qh0.w, hv.w, a0);
    a1 = fmaf(qh1.x, hv.x, a1); a1 = fmaf(qh1.y, hv.y, a1);
    a1 = fmaf(qh1.z, hv.z, a1); a1 = fmaf(qh1.w, hv.w, a1);
  }

  if (tg) { acc_s[tb][tj][0] = a0; acc_s[tb][tj][1] = a1; }
  __syncthreads();
  if (!tg) {
    float gi = sigm(a0), gf = sigm(a1);
    float gg = tanhf(acc_s[tb][tj][0]);
    float go = sigm(acc_s[tb][tj][1]);
    int off = b * HID + j;
    float cv = fmaf(gf, c[off], gi * gg);
    c[off] = cv;
    h_nxt[off] = go * tanhf(cv);
  }
}

// MLP head: out[b] = fc2_w . relu(fc1_w @ h[b] + fc1_b) + fc2_b
__global__ __launch_bounds__(128) void k_fc(
    const float* __restrict__ hfin,
    const void* __restrict__ fc1w, const void* __restrict__ fc1b,
    const void* __restrict__ fc2w, const void* __restrict__ fc2b,
    const int* __restrict__ flag, void* __restrict__ out) {
  int b = blockIdx.x, j = threadIdx.x;  // 128 threads
  __shared__ float red[128];
  const float* h = hfin + b * HID;
  int isbf = flag[0];
  float acc = isbf ? bf1(((const u16*)fc1b)[j]) : ((const float*)fc1b)[j];
  if (isbf) {
    const u16* w = (const u16*)fc1w + j * HID;
    for (int k = 0; k < HID; k++) acc = fmaf(bf1(w[k]), h[k], acc);
  } else {
    const float* w = (const float*)fc1w + j * HID;
    for (int k = 0; k < HID; k++) acc = fmaf(w[k], h[k], acc);
  }
  acc = fmaxf(acc, 0.f);
  float w2 = isbf ? bf1(((const u16*)fc2w)[j]) : ((const float*)fc2w)[j];
  red[j] = acc * w2;
  __syncthreads();
  for (int s = 64; s > 0; s >>= 1) {
    if (j < s) red[j] += red[j + s];
    __syncthreads();
  }
  if (j == 0) {
    float b2 = isbf ? bf1(((const u16*)fc2b)[0]) : ((const float*)fc2b)[0];
    float r = red[0] + b2;
    if (isbf) ((u16*)out)[b] = f2bf(r);
    else      ((float*)out)[b] = r;
  }
}

extern "C" void kernel_launch(void* const* d_in, const int* in_sizes, int n_in,
                              void* d_out, int out_size, void* d_ws, size_t ws_size,
                              hipStream_t stream) {
  const int* ids   = (const int*)d_in[0];
  const void* emb  = d_in[1];
  const void* wih0 = d_in[2];
  const void* whh0 = d_in[3];
  const void* bih0 = d_in[4];
  const void* bhh0 = d_in[5];
  const void* wih1 = d_in[6];
  const void* whh1 = d_in[7];
  const void* bih1 = d_in[8];
  const void* bhh1 = d_in[9];
  const void* fc1w = d_in[10];
  const void* fc1b = d_in[11];
  const void* fc2w = d_in[12];
  const void* fc2b = d_in[13];

  float* ws = (float*)d_ws;
  int*   flag    = (int*)ws;                  // 16-float pad
  float* W0emb   = ws + 16;                   // 27648
  float* whh0_f  = W0emb  + VOC * GATES;      // 262144
  float* wih1_f  = whh0_f + GATES * HID;      // 262144
  float* whh1_f  = wih1_f + GATES * HID;      // 262144
  float* bih1_f  = whh1_f + GATES * HID;      // 1024
  float* bhh1_f  = bih1_f + GATES;            // 1024
  float* h0A = bhh1_f + GATES;                // 65536 each below
  float* h0B = h0A + BATCH * HID;
  float* c0  = h0B + BATCH * HID;
  float* h1A = c0  + BATCH * HID;
  float* h1B = h1A + BATCH * HID;
  float* c1  = h1B + BATCH * HID;

  k_detect<<<1, 64, 0, stream>>>((const u16*)bih0, flag);

  k_convert<<<(GATES * HID + 255) / 256, 256, 0, stream>>>(whh0, whh0_f, GATES * HID, flag);
  k_convert<<<(GATES * HID + 255) / 256, 256, 0, stream>>>(wih1, wih1_f, GATES * HID, flag);
  k_convert<<<(GATES * HID + 255) / 256, 256, 0, stream>>>(whh1, whh1_f, GATES * HID, flag);
  k_convert<<<(GATES + 255) / 256, 256, 0, stream>>>(bih1, bih1_f, GATES, flag);
  k_convert<<<(GATES + 255) / 256, 256, 0, stream>>>(bhh1, bhh1_f, GATES, flag);

  hipMemsetAsync(h0A, 0, (size_t)6 * BATCH * HID * sizeof(float), stream);

  k_prep<<<(VOC * GATES + 255) / 256, 256, 0, stream>>>(emb, wih0, bih0, bhh0, flag, W0emb);

  for (int t = 0; t < TT; t++) {
    const float* h0c = (t & 1) ? h0B : h0A;
    float*       h0n = (t & 1) ? h0A : h0B;
    k_step0<<<256, 512, 0, stream>>>(ids, W0emb, whh0_f, h0c, h0n, c0, t);
    const float* h1c = (t & 1) ? h1B : h1A;
    float*       h1n = (t & 1) ? h1A : h1B;
    k_step1<<<256, 512, 0, stream>>>(h0n, wih1_f, whh1_f, bih1_f, bhh1_f, h1c, h1n, c1);
  }
  // t=511 is odd -> final hidden state written into h1A
  k_fc<<<BATCH, 128, 0, stream>>>(h1A, fc1w, fc1b, fc2w, fc2b, flag, d_out);
}